// Round 8
// baseline (282.229 us; speedup 1.0000x reference)
//
#include <hip/hip_runtime.h>
#include <math.h>

// Qwen3Attention: T=2048, HID=2048, H=16, KV=8, D=128
#define T_TOK 2048
#define HID 2048
#define NH 16
#define NKV 8
#define HD 128
#define QKV_N 4096
#define EPS 1e-6f

typedef unsigned short u16;
typedef unsigned int   u32;
typedef __attribute__((ext_vector_type(8))) u16   u16x8;
typedef __attribute__((ext_vector_type(8))) short short8;
typedef __attribute__((ext_vector_type(4))) float floatx4;
typedef __attribute__((ext_vector_type(16))) float f32x16;
typedef __attribute__((ext_vector_type(4))) u32   u32x4;

__device__ __forceinline__ u16 f2bf(float x) {           // RNE f32->bf16
    u32 u = __float_as_uint(x);
    u = (u + 0x7fffu + ((u >> 16) & 1u)) >> 16;
    return (u16)u;
}
__device__ __forceinline__ float bf2f(u16 h) {
    return __uint_as_float(((u32)h) << 16);
}
__device__ __forceinline__ u32 cvtpk_bf16(float lo, float hi) {
    u32 r;
    asm("v_cvt_pk_bf16_f32 %0, %1, %2" : "=v"(r) : "v"(lo), "v"(hi));
    return r;
}

// ---------------------------------------------------------------------------
// f32 -> bf16, 8 elems/thread helper.
// ---------------------------------------------------------------------------
__device__ __forceinline__ void cvt8(const float* __restrict__ in,
                                     u16* __restrict__ out, size_t i)
{
    float4 a = *(const float4*)(in + i);
    float4 b = *(const float4*)(in + i + 4);
    u16x8 o;
    o[0] = f2bf(a.x); o[1] = f2bf(a.y); o[2] = f2bf(a.z); o[3] = f2bf(a.w);
    o[4] = f2bf(b.x); o[5] = f2bf(b.y); o[6] = f2bf(b.z); o[7] = f2bf(b.w);
    *(u16x8*)(out + i) = o;
}

// hidden (2048 blk) + qkv_w (4096 blk) in one launch.
__global__ __launch_bounds__(256) void cvt_pair(
    const float* __restrict__ ina, u16* __restrict__ outa,
    const float* __restrict__ inb, u16* __restrict__ outb)
{
    const int bid = blockIdx.x;
    if (bid < 2048) cvt8(ina, outa, ((size_t)bid * 256 + threadIdx.x) * 8);
    else            cvt8(inb, outb, ((size_t)(bid - 2048) * 256 + threadIdx.x) * 8);
}

// out += part (f32), 8 elems/thread.
__global__ __launch_bounds__(256) void addf32(
    float* __restrict__ out, const float* __restrict__ part)
{
    const size_t i = ((size_t)blockIdx.x * 256 + threadIdx.x) * 8;
    float4 a0 = *(const float4*)(out + i);
    float4 a1 = *(const float4*)(out + i + 4);
    float4 b0 = *(const float4*)(part + i);
    float4 b1 = *(const float4*)(part + i + 4);
    a0.x += b0.x; a0.y += b0.y; a0.z += b0.z; a0.w += b0.w;
    a1.x += b1.x; a1.y += b1.y; a1.z += b1.z; a1.w += b1.w;
    *(float4*)(out + i)     = a0;
    *(float4*)(out + i + 4) = a1;
}

// ---------------------------------------------------------------------------
// bf16 MFMA GEMM, T2+T3+T4+T5 stack: C[M,N] = A[M,K]*B[N,K]^T
// Split-K via blockIdx.z: z selects k-offset z*Ks and target (z? Cv2 : Cv).
// ---------------------------------------------------------------------------
#define GBM 256
#define GBN 128
#define GBK 64
#define BUFSH 24576

#define WAITV6 asm volatile("s_waitcnt vmcnt(6)" ::: "memory")
#define WAITV0 asm volatile("s_waitcnt vmcnt(0)" ::: "memory")
#define LGKM0  asm volatile("s_waitcnt lgkmcnt(0)" ::: "memory")
#define BARR   asm volatile("s_barrier" ::: "memory")
#define SB     __builtin_amdgcn_sched_barrier(0)

#define STAGEU(i, tt, dstb) \
    __builtin_amdgcn_global_load_lds( \
        (const __attribute__((address_space(1))) u32*)(gsrc[i] + (size_t)(tt)*GBK), \
        (__attribute__((address_space(3))) u32*)((dstb) + loff[i]), 16, 0, 0)

#define RD_A(dst, srcb, f) do { \
    dst[0] = *(const short8*)((srcb) + arow + (f)*1024 + achunk0); \
    dst[1] = *(const short8*)((srcb) + arow + (f)*1024 + achunk1); } while (0)

#define RD_B(dst, srcb) do { \
    _Pragma("unroll") \
    for (int j_ = 0; j_ < 4; ++j_) { \
        dst[j_][0] = *(const short8*)((srcb) + 16384 + brow + j_*1024 + achunk0); \
        dst[j_][1] = *(const short8*)((srcb) + 16384 + brow + j_*1024 + achunk1); } } while (0)

#define MM(f, aa, bb) do { \
    __builtin_amdgcn_s_setprio(1); \
    _Pragma("unroll") \
    for (int j_ = 0; j_ < 4; ++j_) { \
        acc[f][j_] = __builtin_amdgcn_mfma_f32_16x16x32_bf16(aa[0], bb[j_][0], acc[f][j_], 0, 0, 0); \
        acc[f][j_] = __builtin_amdgcn_mfma_f32_16x16x32_bf16(aa[1], bb[j_][1], acc[f][j_], 0, 0, 0); } \
    __builtin_amdgcn_s_setprio(0); } while (0)

#define TILE(t, CURB, NXTB, THDB, BBC, BBN) do { \
    const bool st_ = (t) + 2 < nt; \
    if (st_) { STAGEU(0, (t)+2, THDB); STAGEU(1, (t)+2, THDB); } \
    RD_A(aP1, CURB, 1); SB; \
    MM(0, aP0, BBC); SB; \
    if (st_) { STAGEU(2, (t)+2, THDB); STAGEU(3, (t)+2, THDB); } \
    RD_A(aP0, CURB, 2); SB; \
    MM(1, aP1, BBC); SB; \
    if (st_) { STAGEU(4, (t)+2, THDB); STAGEU(5, (t)+2, THDB); } \
    RD_A(aP1, CURB, 3); SB; \
    MM(2, aP0, BBC); \
    if ((t) + 1 < nt) { \
        if (st_) { WAITV6; } else { WAITV0; } \
        LGKM0; BARR; SB; \
        RD_B(BBN, NXTB); RD_A(aP0, NXTB, 0); \
    } \
    SB; \
    MM(3, aP1, BBC); SB; \
} while (0)

template<bool OUT_BF16>
__global__ __launch_bounds__(512, 2) void gemm_bt_8p(
    const u16* __restrict__ A, const u16* __restrict__ B,
    void* __restrict__ Cv, void* __restrict__ Cv2,
    int Ks, int lda, int ldb, int ldc)
{
    extern __shared__ short lds[];
    const int tid = threadIdx.x;
    const int w  = tid >> 6;
    const int l  = tid & 63;
    const int m0 = blockIdx.y * GBM;
    const int n0 = blockIdx.x * GBN;
    const int z  = blockIdx.z;
    A += (size_t)z * Ks;                    // k-offset within rows
    B += (size_t)z * Ks;
    void* Cw = z ? Cv2 : Cv;
    const int mr = (w >> 1) * 64;
    const int nc = (w & 1) * 64;
    const int cc = l & 15;
    const int q4 = l >> 4;

    const int lr = l >> 3;
    const int gchunk = ((l & 7) ^ (lr & 7)) * 8;
    const u16* gsrc[6]; int loff[6];
    #pragma unroll
    for (int i = 0; i < 6; ++i) {
        const int u = w * 6 + i;
        if (u < 32) {
            gsrc[i] = A + (size_t)(m0 + u*8 + lr) * lda + gchunk;
            loff[i] = u * 512;
        } else {
            const int v = u - 32;
            gsrc[i] = B + (size_t)(n0 + v*8 + lr) * ldb + gchunk;
            loff[i] = 16384 + v * 512;
        }
    }

    const int achunk0 = ((q4)     ^ (cc & 7)) * 8;
    const int achunk1 = ((4 + q4) ^ (cc & 7)) * 8;
    const int arow = (mr + cc) * 64;
    const int brow = (nc + cc) * 64;

    floatx4 acc[4][4];
    #pragma unroll
    for (int f = 0; f < 4; ++f)
        #pragma unroll
        for (int j = 0; j < 4; ++j) acc[f][j] = (floatx4){0.f, 0.f, 0.f, 0.f};

    short8 aP0[2], aP1[2], bbE[4][2], bbO[4][2];
    short* b0 = lds;
    short* b1 = lds + BUFSH;
    short* b2 = lds + 2 * BUFSH;
    const int nt = Ks >> 6;

    #pragma unroll
    for (int i = 0; i < 6; ++i) STAGEU(i, 0, b0);
    #pragma unroll
    for (int i = 0; i < 6; ++i) STAGEU(i, 1, b1);
    WAITV6; BARR; SB;
    RD_B(bbE, b0); RD_A(aP0, b0, 0);

    short *CURB = b0, *NXTB = b1, *THDB = b2;
    for (int t = 0; t < nt; t += 2) {
        TILE(t, CURB, NXTB, THDB, bbE, bbO);
        { short* tmp = CURB; CURB = NXTB; NXTB = THDB; THDB = tmp; }
        TILE(t + 1, CURB, NXTB, THDB, bbO, bbE);
        { short* tmp = CURB; CURB = NXTB; NXTB = THDB; THDB = tmp; }
    }

    const int r0 = q4 * 4;
    #pragma unroll
    for (int f = 0; f < 4; ++f)
        #pragma unroll
        for (int j = 0; j < 4; ++j)
            #pragma unroll
            for (int r = 0; r < 4; ++r) {
                const int row = m0 + mr + f*16 + r0 + r;
                const int col = n0 + nc + j*16 + cc;
                if (OUT_BF16)
                    ((u16*)Cw)[(size_t)row * ldc + col] = f2bf(acc[f][j][r]);
                else
                    ((float*)Cw)[(size_t)row * ldc + col] = acc[f][j][r];
            }
}

// ---------------------------------------------------------------------------
// Fused prep: RMSNorm+RoPE q/K (q in place, K packed swizzled) + V
// transpose-pack (64-s layout). 256 blocks: tile = bid&31, kvh = bid>>5.
// ---------------------------------------------------------------------------
__global__ __launch_bounds__(256) void prep(
    u16* __restrict__ qkv, const int* __restrict__ positions,
    const float* __restrict__ qw, const float* __restrict__ kw,
    u16* __restrict__ Kp, u16* __restrict__ Vtp)
{
    const int bid = blockIdx.x;
    const int tile = bid & 31, kvh = bid >> 5;
    const int tid = threadIdx.x;
    const int w = tid >> 6, l = tid & 63;
    const int t0 = tile * 64;

    const float qw0 = qw[2*l], qw1 = qw[2*l+1];
    const float kw0 = kw[2*l], kw1 = kw[2*l+1];
    const int   i0  = (2*l) & 63;
    const float if0 = exp2f(-(float)i0     * 0.311430758895690f); // log2(1e6)/64
    const float if1 = exp2f(-(float)(i0+1) * 0.311430758895690f);

    for (int rr = w; rr < 64; rr += 4) {
        const int t = t0 + rr;
        const int pos = positions[t];
        const float a0 = (float)pos * if0;
        const float a1 = (float)pos * if1;
        const float s0 = sinf(a0), c0 = cosf(a0);
        const float s1 = sinf(a1), c1 = cosf(a1);

        #pragma unroll
        for (int pass = 0; pass < 3; ++pass) {
            const int off = (pass < 2) ? (2*kvh + pass)*HD : NH*HD + kvh*HD;
            const float w0 = (pass < 2) ? qw0 : kw0;
            const float w1 = (pass < 2) ? qw1 : kw1;
            u16* p = qkv + (size_t)t*QKV_N + off;

            const u32 pk = *(const u32*)(p + 2*l);
            const float x0 = bf2f((u16)pk), x1 = bf2f((u16)(pk >> 16));
            float ss = x0*x0 + x1*x1;
            #pragma unroll
            for (int x = 1; x < 64; x <<= 1) ss += __shfl_xor(ss, x);
            const float rs = rsqrtf(ss * (1.0f/128.0f) + EPS);
            const float xn0 = x0 * rs * w0, xn1 = x1 * rs * w1;
            const float px0 = __shfl_xor(xn0, 32);
            const float px1 = __shfl_xor(xn1, 32);

            float o0, o1;
            if (l < 32) { o0 = xn0*c0 - px0*s0; o1 = xn1*c1 - px1*s1; }
            else        { o0 = xn0*c0 + px0*s0; o1 = xn1*c1 + px1*s1; }
            const u32 outpk = (u32)f2bf(o0) | ((u32)f2bf(o1) << 16);

            if (pass < 2) {
                *(u32*)(p + 2*l) = outpk;
            } else {
                const int ch = l >> 2;
                u16* dst = Kp + ((size_t)(kvh*32 + tile)*64 + rr)*128
                              + (ch ^ (rr & 15))*8 + (l & 3)*2;
                *(u32*)dst = outpk;
            }
        }
    }

    // ---- V transpose + swizzled pack (64-s layout) ----
    __shared__ u16 tl[64][136];
    {
        const int t  = tid >> 2;
        const int c0 = (tid & 3) * 32;
        const u16* src = qkv + (size_t)(t0 + t)*QKV_N + NH*HD + NKV*HD + kvh*HD + c0;
        #pragma unroll
        for (int p2 = 0; p2 < 4; ++p2)
            *(u16x8*)(&tl[t][c0 + p2*8]) = *(const u16x8*)(src + p2*8);
    }
    __syncthreads();
    {
        u16* dstb = Vtp + (size_t)(kvh*32 + tile) * 128 * 64;
        #pragma unroll
        for (int i = 0; i < 4; ++i) {
            const int id = tid*4 + i;
            const int d = id >> 3;
            const int o = id & 7;
            const int sb = (o ^ (d & 7)) * 8;
            u16x8 v;
            #pragma unroll
            for (int j = 0; j < 8; ++j) v[j] = tl[sb + j][d];
            *(u16x8*)(dstb + d*64 + o*8) = v;
        }
    }
}

// ---------------------------------------------------------------------------
// 32x32-MFMA flash attention, 8-WAVE BLOCKS: 512 thr, q-tile=256 (32 q/wave
// -- per-wave code and register footprint BIT-IDENTICAL to the proven
// round-2 kernel, VGPR 112), kv-tile=64 double-buffered, one head/block.
// 8 waves share each staged K/V tile -> tile-visits halve chip-wide
// (4352 -> 2304 serial chains) at constant per-CU LDS-read bytes.
// Split-s 4 parts (nt = 4qt+4 divides evenly). 2 blocks/CU (64 KB LDS,
// 16 waves/CU). grid 512 = 8 kvh x 2 hp x 4 part x 4 q3 x 2 top;
// top pairs qt = q3 with 7-q3 so co-resident pairs sum to 9 tiles.
// ---------------------------------------------------------------------------
__global__ __launch_bounds__(512, 4) void attn_mfma32(
    const u16* __restrict__ qkv, const u16* __restrict__ Kp,
    const u16* __restrict__ Vtp,
    u16* __restrict__ P0, u16* __restrict__ P1,
    u16* __restrict__ P2, u16* __restrict__ P3,
    float2* __restrict__ ml)
{
    const int id  = blockIdx.x;          // 0..511
    const int kvh = id & 7;
    const int u   = id >> 3;             // 0..63
    const int hp  = u & 1;
    const int p   = (u >> 1) & 3;        // split-s part
    const int q3  = (u >> 3) & 3;
    const int top = u >> 5;
    const int qt  = top ? 7 - q3 : q3;   // 0..7, q-tile of 256 rows
    const int h   = kvh*2 + hp;
    const int t0q = qt * 256;

    const int tid = threadIdx.x;
    const int w   = tid >> 6;       // wave 0..7 owns q rows [w*32, w*32+32)
    const int l   = tid & 63;
    const int q31 = l & 31;
    const int hi  = l >> 5;

    __shared__ short Ks[2][8192];   // 2 x 16 KB (64 kv x 128 d, chunk-swz)
    __shared__ short Vts[2][8192];  // 2 x 16 KB (128 d x 64 s, chunk-swz)

    // ---- Q B-frags in registers ----
    short8 qf[8];
    {
        const u16* qrow = qkv + (size_t)(t0q + w*32 + q31) * QKV_N + h*HD;
        #pragma unroll
        for (int ks = 0; ks < 8; ++ks)
            qf[ks] = *(const short8*)(qrow + ks*16 + hi*8);
    }

    float m_run = -3.0e38f, l_run = 0.f;
    f32x16 accO[4];                 // O[q rows via reg][d = nd*32 + q31]
    #pragma unroll
    for (int nd = 0; nd < 4; ++nd)
        #pragma unroll
        for (int r = 0; r < 16; ++r) accO[nd][r] = 0.f;

    const float Cs = 0.12751744f;   // (1/sqrt(128)) * log2(e)

    const int nt  = 4*qt + 4;
    const int tlo = p * (qt + 1);   // nt/4 == qt+1 exactly
    const int thi = tlo + (qt + 1);

    // 8 waves stage 32 KB: waves 0-3 K image, waves 4-7 Vt image (4 KB each).
    auto issue = [&](int tile, int buf) {
        const size_t tb = (size_t)(kvh*32 + tile) * 8192;
        const u16* g = ((w < 4) ? Kp : Vtp) + tb + (w & 3)*2048 + l*8;
        short* pl = ((w < 4) ? Ks[buf] : Vts[buf]) + (w & 3)*2048 + l*8;
        #pragma unroll
        for (int i = 0; i < 4; ++i)
            __builtin_amdgcn_global_load_lds(
                (const __attribute__((address_space(1))) u32*)(g + i*512),
                (__attribute__((address_space(3))) u32*)(pl + i*512), 16, 0, 0);
    };

    issue(tlo, 0);
    int cur = 0;

    for (int tile = tlo; tile < thi; ++tile) {
        __syncthreads();            // drains buf[cur] DMA
        if (tile + 1 < thi) issue(tile + 1, cur ^ 1);

        const short* Kc = Ks[cur];
        const short* Vc = Vts[cur];

        // ---- S^T = K Q^T ----
        f32x16 accS0, accS1;
        #pragma unroll
        for (int r = 0; r < 16; ++r) { accS0[r] = 0.f; accS1[r] = 0.f; }

        __builtin_amdgcn_s_setprio(1);
        #pragma unroll
        for (int ks = 0; ks < 8; ++ks) {
            const int pc = ((2*ks + hi) ^ (q31 & 15)) * 8;
            short8 a0 = *(const short8*)(Kc + q31*128 + pc);
            short8 a1 = *(const short8*)(Kc + (32 + q31)*128 + pc);
            accS0 = __builtin_amdgcn_mfma_f32_32x32x16_bf16(a0, qf[ks], accS0, 0, 0, 0);
            accS1 = __builtin_amdgcn_mfma_f32_32x32x16_bf16(a1, qf[ks], accS1, 0, 0, 0);
        }
        __builtin_amdgcn_s_setprio(0);

        // ---- causal mask (diagonal region: tile >= 4*qt) ----
        if (tile >= 4*qt) {
            const int qg   = t0q + w*32 + q31;
            const int kvb0 = tile*64 + (hi << 2);
            #pragma unroll
            for (int r = 0; r < 16; ++r) {
                const int kvg = kvb0 + (r&3) + 8*(r>>2);
                if (kvg > qg)      accS0[r] = -1.0e30f;
                if (kvg + 32 > qg) accS1[r] = -1.0e30f;
            }
        }

        // ---- online softmax (per q col = lane pair l, l^32) ----
        float mx = accS0[0];
        #pragma unroll
        for (int r = 1; r < 16; ++r) mx = fmaxf(mx, accS0[r]);
        #pragma unroll
        for (int r = 0; r < 16; ++r) mx = fmaxf(mx, accS1[r]);
        mx = fmaxf(mx, __shfl_xor(mx, 32));

        if (__any(mx > m_run + 11.76f)) {   // T13 defer-max
            const float m_new = fmaxf(m_run, mx);
            const float alpha = exp2f((m_run - m_new) * Cs);
            l_run *= alpha;
            m_run = m_new;
            #pragma unroll
            for (int r = 0; r < 16; ++r) {
                const float ar = __shfl(alpha, ((r&3) + 8*(r>>2)) + (hi<<2));
                accO[0][r] *= ar; accO[1][r] *= ar;
                accO[2][r] *= ar; accO[3][r] *= ar;
            }
        }

        const float mb = m_run * Cs;
        float lsum = 0.f;
        #pragma unroll
        for (int r = 0; r < 16; ++r) {
            const float e0 = exp2f(accS0[r]*Cs - mb);
            const float e1 = exp2f(accS1[r]*Cs - mb);
            accS0[r] = e0; accS1[r] = e1;
            lsum += e0 + e1;
        }
        lsum += __shfl_xor(lsum, 32);
        l_run += lsum;

        // ---- PV: O[q][d] += P[q][s] Vt[d][s]; A-frag via cvt_pk+permlane ----
        __builtin_amdgcn_s_setprio(1);
        #pragma unroll
        for (int ks = 0; ks < 4; ++ks) {
            const int R = (ks & 1) * 8;
            u32 x0, x1, x2, x3;
            if (ks < 2) {
                x0 = cvtpk_bf16(accS0[R+0], accS0[R+1]);
                x1 = cvtpk_bf16(accS0[R+2], accS0[R+3]);
                x2 = cvtpk_bf16(accS0[R+4], accS0[R+5]);
                x3 = cvtpk_bf16(accS0[R+6], accS0[R+7]);
            } else {
                x0 = cvtpk_bf16(accS1[R+0], accS1[R+1]);
                x1 = cvtpk_bf16(accS1[R+2], accS1[R+3]);
                x2 = cvtpk_bf16(accS1[R+4], accS1[R+5]);
                x3 = cvtpk_bf16(accS1[R+6], accS1[R+7]);
            }
            asm("v_permlane32_swap_b32 %0, %1" : "+v"(x0), "+v"(x2));
            asm("v_permlane32_swap_b32 %0, %1" : "+v"(x1), "+v"(x3));
            u32x4 aw; aw.x = x0; aw.y = x1; aw.z = x2; aw.w = x3;
            const short8 aP = __builtin_bit_cast(short8, aw);
            #pragma unroll
            for (int nd = 0; nd < 4; ++nd) {
                short8 bv = *(const short8*)(Vc + (nd*32 + q31)*64
                                             + ((2*ks + hi) ^ (q31 & 7))*8);
                accO[nd] = __builtin_amdgcn_mfma_f32_32x32x16_bf16(aP, bv, accO[nd], 0, 0, 0);
            }
        }
        __builtin_amdgcn_s_setprio(0);

        cur ^= 1;
    }

    // ---- write UNNORMALIZED partial + (m,l) per q row ----
    u16* Op = (p == 0) ? P0 : (p == 1) ? P1 : (p == 2) ? P2 : P3;
    const size_t hb = (size_t)h * T_TOK;
    #pragma unroll
    for (int r = 0; r < 16; ++r) {
        const int qr = (r&3) + 8*(r>>2) + (hi<<2);
        u16* op = Op + (hb + t0q + w*32 + qr) * HD;
        op[q31]      = f2bf(accO[0][r]);
        op[32 + q31] = f2bf(accO[1][r]);
        op[64 + q31] = f2bf(accO[2][r]);
        op[96 + q31] = f2bf(accO[3][r]);
    }
    if (l < 32)
        ml[(size_t)p*NH*T_TOK + hb + t0q + w*32 + l]
            = make_float2(m_run, l_run);
}

// ---------------------------------------------------------------------------
// Merge the four split-s partials -> q slot of qkv (bf16), 8 elems/thread,
// blocks [0,2048). Blocks [2048,4096): o_w f32->bf16 cvt into kpb.
// ---------------------------------------------------------------------------
__global__ __launch_bounds__(256) void combine4_cvt(
    const u16* __restrict__ P0, const u16* __restrict__ P1,
    const u16* __restrict__ P2, const u16* __restrict__ P3,
    const float2* __restrict__ ml, u16* __restrict__ qkv,
    const float* __restrict__ ow, u16* __restrict__ owbf)
{
    const int bid = blockIdx.x;
    if (bid >= 2048) {
        cvt8(ow, owbf, ((size_t)(bid - 2048) * 256 + threadIdx.x) * 8);
        return;
    }
    const int idx = bid * 256 + threadIdx.x;
    const int c16 = idx & 15;
    const int t   = (idx >> 4) & (T_TOK - 1);
    const int h   = idx >> 15;
    const size_t base = (size_t)h * T_TOK + t;
    const size_t NT = (size_t)NH * T_TOK;
    const float2 a = ml[base];
    const float2 b = ml[base + NT];
    const float2 c = ml[base + 2*NT];
    const float2 d = ml[base + 3*NT];
    const float Cs = 0.12751744f;
    const float mM = fmaxf(fmaxf(a.x, b.x), fmaxf(c.x, d.x));
    const float wA = exp2f((a.x - mM) * Cs);
    const float wB = exp2f((b.x - mM) * Cs);
    const float wC = exp2f((c.x - mM) * Cs);
    const float wD = exp2f((d.x - mM) * Cs);
    const float inv = 1.0f / (wA*a.y + wB*b.y + wC*c.y + wD*d.y);
    const u16x8 A = *(const u16x8*)(P0 + base * HD + c16*8);
    const u16x8 B = *(const u16x8*)(P1 + base * HD + c16*8);
    const u16x8 C = *(const u16x8*)(P2 + base * HD + c16*8);
    const u16x8 D = *(const u16x8*)(P3 + base * HD + c16*8);
    u16x8 o;
    #pragma unroll
    for (int j = 0; j < 8; ++j)
        o[j] = f2bf((wA*bf2f(A[j]) + wB*bf2f(B[j]) + wC*bf2f(C[j]) + wD*bf2f(D[j])) * inv);
    *(u16x8*)(qkv + (size_t)t * QKV_N + h * HD + c16*8) = o;
}

// ---------------------------------------------------------------------------
extern "C" void kernel_launch(void* const* d_in, const int* in_sizes, int n_in,
                              void* d_out, int out_size, void* d_ws, size_t ws_size,
                              hipStream_t stream)
{
    const float* hidden    = (const float*)d_in[0];   // T x HID
    const int*   positions = (const int*)  d_in[1];   // T
    const float* qkv_w     = (const float*)d_in[2];   // 4096 x 2048
    const float* o_w       = (const float*)d_in[3];   // 2048 x 2048
    const float* q_norm_w  = (const float*)d_in[4];   // 128
    const float* k_norm_w  = (const float*)d_in[5];   // 128
    float* out = (float*)d_out;                       // T x HID (f32)

    // ws: [qkvbf 16MB][wbf 16MB][abf 8MB][kpb 4MB][vpb 4MB] = 48 MB
    // During attn: P0/P1 -> wbf halves, P2 -> abf, P3 -> out[0:8MB],
    // ml -> out[8:12MB]. o_w bf16 -> kpb+vpb (8 MB) during combine launch.
    // gemm2: B = kpb, split-K partial -> wbf (dead after combine).
    u16* qkvbf = (u16*)d_ws;
    u16* wbf   = qkvbf + (size_t)T_TOK * QKV_N;
    u16* abf   = wbf   + (size_t)QKV_N * HID;
    u16* kpb   = abf   + (size_t)T_TOK * HID;
    u16* vpb   = kpb   + (size_t)NKV * T_TOK * HD;

    u16* P0 = wbf;
    u16* P1 = wbf + (size_t)NH * T_TOK * HD;   // wbf second half
    u16* P2 = abf;
    u16* P3 = (u16*)out;
    float2* mlp = (float2*)((u16*)out + (size_t)NH * T_TOK * HD);
    float* partC = (float*)wbf;     // 2048x2048 f32 = 16 MB (fits wbf exactly)

    static bool s_attr = false;
    if (!s_attr) {
        (void)hipFuncSetAttribute(
            reinterpret_cast<const void*>(&gemm_bt_8p<true>),
            hipFuncAttributeMaxDynamicSharedMemorySize, 147456);
        (void)hipFuncSetAttribute(
            reinterpret_cast<const void*>(&gemm_bt_8p<false>),
            hipFuncAttributeMaxDynamicSharedMemorySize, 147456);
        s_attr = true;
    }

    // 0) hidden + qkv_w -> bf16 (one launch)
    cvt_pair<<<6144, 256, 0, stream>>>(hidden, abf, qkv_w, wbf);

    // 1) qkv(bf16) = hidden @ qkv_w^T   (no k-split)
    gemm_bt_8p<true><<<dim3(QKV_N/GBN, T_TOK/GBM, 1), 512, 147456, stream>>>(
        abf, wbf, qkvbf, qkvbf, HID, HID, HID, QKV_N);

    // 2) prep (rmsnorm+rope, K/V pack; V 64-s layout)
    prep<<<256, 256, 0, stream>>>(qkvbf, positions, q_norm_w, k_norm_w, kpb, vpb);

    // 3) 8-wave q-tile-256 split-4 flash attention (2 blocks/CU, no spill)
    attn_mfma32<<<512, 512, 0, stream>>>(qkvbf, kpb, vpb, P0, P1, P2, P3, mlp);

    // 3b) combine partials -> q slots of qkv; o_w -> bf16 into kpb(+vpb)
    combine4_cvt<<<4096, 256, 0, stream>>>(P0, P1, P2, P3, mlp, qkvbf, o_w, kpb);

    // 4) out(f32) = o @ o_w^T, split-K=2 over z: z=0 -> out, z=1 -> partC
    gemm_bt_8p<false><<<dim3(HID/GBN, T_TOK/GBM, 2), 512, 147456, stream>>>(
        qkvbf, kpb, out, partC, HID/2, QKV_N, HID, HID);

    // 4b) out += partC
    addf32<<<(T_TOK*HID)/2048, 256, 0, stream>>>(out, partC);
}

// Round 9
// 246.093 us; speedup vs baseline: 1.1468x; 1.1468x over previous
//
#include <hip/hip_runtime.h>
#include <math.h>

// Qwen3Attention: T=2048, HID=2048, H=16, KV=8, D=128
#define T_TOK 2048
#define HID 2048
#define NH 16
#define NKV 8
#define HD 128
#define QKV_N 4096
#define EPS 1e-6f

typedef unsigned short u16;
typedef unsigned int   u32;
typedef __attribute__((ext_vector_type(8))) u16   u16x8;
typedef __attribute__((ext_vector_type(8))) short short8;
typedef __attribute__((ext_vector_type(4))) float floatx4;
typedef __attribute__((ext_vector_type(16))) float f32x16;
typedef __attribute__((ext_vector_type(4))) u32   u32x4;

__device__ __forceinline__ u16 f2bf(float x) {           // RNE f32->bf16
    u32 u = __float_as_uint(x);
    u = (u + 0x7fffu + ((u >> 16) & 1u)) >> 16;
    return (u16)u;
}
__device__ __forceinline__ float bf2f(u16 h) {
    return __uint_as_float(((u32)h) << 16);
}
__device__ __forceinline__ u32 cvtpk_bf16(float lo, float hi) {
    u32 r;
    asm("v_cvt_pk_bf16_f32 %0, %1, %2" : "=v"(r) : "v"(lo), "v"(hi));
    return r;
}

// ---------------------------------------------------------------------------
// f32 -> bf16, 8 elems/thread helper.
// ---------------------------------------------------------------------------
__device__ __forceinline__ void cvt8(const float* __restrict__ in,
                                     u16* __restrict__ out, size_t i)
{
    float4 a = *(const float4*)(in + i);
    float4 b = *(const float4*)(in + i + 4);
    u16x8 o;
    o[0] = f2bf(a.x); o[1] = f2bf(a.y); o[2] = f2bf(a.z); o[3] = f2bf(a.w);
    o[4] = f2bf(b.x); o[5] = f2bf(b.y); o[6] = f2bf(b.z); o[7] = f2bf(b.w);
    *(u16x8*)(out + i) = o;
}

// hidden (2048 blk) + qkv_w (4096 blk) in one launch.
__global__ __launch_bounds__(256) void cvt_pair(
    const float* __restrict__ ina, u16* __restrict__ outa,
    const float* __restrict__ inb, u16* __restrict__ outb)
{
    const int bid = blockIdx.x;
    if (bid < 2048) cvt8(ina, outa, ((size_t)bid * 256 + threadIdx.x) * 8);
    else            cvt8(inb, outb, ((size_t)(bid - 2048) * 256 + threadIdx.x) * 8);
}

// out += part (f32), 8 elems/thread.
__global__ __launch_bounds__(256) void addf32(
    float* __restrict__ out, const float* __restrict__ part)
{
    const size_t i = ((size_t)blockIdx.x * 256 + threadIdx.x) * 8;
    float4 a0 = *(const float4*)(out + i);
    float4 a1 = *(const float4*)(out + i + 4);
    float4 b0 = *(const float4*)(part + i);
    float4 b1 = *(const float4*)(part + i + 4);
    a0.x += b0.x; a0.y += b0.y; a0.z += b0.z; a0.w += b0.w;
    a1.x += b1.x; a1.y += b1.y; a1.z += b1.z; a1.w += b1.w;
    *(float4*)(out + i)     = a0;
    *(float4*)(out + i + 4) = a1;
}

// ---------------------------------------------------------------------------
// bf16 MFMA GEMM, T2+T3+T4+T5 stack: C[M,N] = A[M,K]*B[N,K]^T
// Split-K via blockIdx.z: z selects k-offset z*Ks and target (z? Cv2 : Cv).
// ---------------------------------------------------------------------------
#define GBM 256
#define GBN 128
#define GBK 64
#define BUFSH 24576

#define WAITV6 asm volatile("s_waitcnt vmcnt(6)" ::: "memory")
#define WAITV0 asm volatile("s_waitcnt vmcnt(0)" ::: "memory")
#define LGKM0  asm volatile("s_waitcnt lgkmcnt(0)" ::: "memory")
#define BARR   asm volatile("s_barrier" ::: "memory")
#define SB     __builtin_amdgcn_sched_barrier(0)

#define STAGEU(i, tt, dstb) \
    __builtin_amdgcn_global_load_lds( \
        (const __attribute__((address_space(1))) u32*)(gsrc[i] + (size_t)(tt)*GBK), \
        (__attribute__((address_space(3))) u32*)((dstb) + loff[i]), 16, 0, 0)

#define RD_A(dst, srcb, f) do { \
    dst[0] = *(const short8*)((srcb) + arow + (f)*1024 + achunk0); \
    dst[1] = *(const short8*)((srcb) + arow + (f)*1024 + achunk1); } while (0)

#define RD_B(dst, srcb) do { \
    _Pragma("unroll") \
    for (int j_ = 0; j_ < 4; ++j_) { \
        dst[j_][0] = *(const short8*)((srcb) + 16384 + brow + j_*1024 + achunk0); \
        dst[j_][1] = *(const short8*)((srcb) + 16384 + brow + j_*1024 + achunk1); } } while (0)

#define MM(f, aa, bb) do { \
    __builtin_amdgcn_s_setprio(1); \
    _Pragma("unroll") \
    for (int j_ = 0; j_ < 4; ++j_) { \
        acc[f][j_] = __builtin_amdgcn_mfma_f32_16x16x32_bf16(aa[0], bb[j_][0], acc[f][j_], 0, 0, 0); \
        acc[f][j_] = __builtin_amdgcn_mfma_f32_16x16x32_bf16(aa[1], bb[j_][1], acc[f][j_], 0, 0, 0); } \
    __builtin_amdgcn_s_setprio(0); } while (0)

#define TILE(t, CURB, NXTB, THDB, BBC, BBN) do { \
    const bool st_ = (t) + 2 < nt; \
    if (st_) { STAGEU(0, (t)+2, THDB); STAGEU(1, (t)+2, THDB); } \
    RD_A(aP1, CURB, 1); SB; \
    MM(0, aP0, BBC); SB; \
    if (st_) { STAGEU(2, (t)+2, THDB); STAGEU(3, (t)+2, THDB); } \
    RD_A(aP0, CURB, 2); SB; \
    MM(1, aP1, BBC); SB; \
    if (st_) { STAGEU(4, (t)+2, THDB); STAGEU(5, (t)+2, THDB); } \
    RD_A(aP1, CURB, 3); SB; \
    MM(2, aP0, BBC); \
    if ((t) + 1 < nt) { \
        if (st_) { WAITV6; } else { WAITV0; } \
        LGKM0; BARR; SB; \
        RD_B(BBN, NXTB); RD_A(aP0, NXTB, 0); \
    } \
    SB; \
    MM(3, aP1, BBC); SB; \
} while (0)

template<bool OUT_BF16>
__global__ __launch_bounds__(512, 2) void gemm_bt_8p(
    const u16* __restrict__ A, const u16* __restrict__ B,
    void* __restrict__ Cv, void* __restrict__ Cv2,
    int Ks, int lda, int ldb, int ldc)
{
    extern __shared__ short lds[];
    const int tid = threadIdx.x;
    const int w  = tid >> 6;
    const int l  = tid & 63;
    const int m0 = blockIdx.y * GBM;
    const int n0 = blockIdx.x * GBN;
    const int z  = blockIdx.z;
    A += (size_t)z * Ks;                    // k-offset within rows
    B += (size_t)z * Ks;
    void* Cw = z ? Cv2 : Cv;
    const int mr = (w >> 1) * 64;
    const int nc = (w & 1) * 64;
    const int cc = l & 15;
    const int q4 = l >> 4;

    const int lr = l >> 3;
    const int gchunk = ((l & 7) ^ (lr & 7)) * 8;
    const u16* gsrc[6]; int loff[6];
    #pragma unroll
    for (int i = 0; i < 6; ++i) {
        const int u = w * 6 + i;
        if (u < 32) {
            gsrc[i] = A + (size_t)(m0 + u*8 + lr) * lda + gchunk;
            loff[i] = u * 512;
        } else {
            const int v = u - 32;
            gsrc[i] = B + (size_t)(n0 + v*8 + lr) * ldb + gchunk;
            loff[i] = 16384 + v * 512;
        }
    }

    const int achunk0 = ((q4)     ^ (cc & 7)) * 8;
    const int achunk1 = ((4 + q4) ^ (cc & 7)) * 8;
    const int arow = (mr + cc) * 64;
    const int brow = (nc + cc) * 64;

    floatx4 acc[4][4];
    #pragma unroll
    for (int f = 0; f < 4; ++f)
        #pragma unroll
        for (int j = 0; j < 4; ++j) acc[f][j] = (floatx4){0.f, 0.f, 0.f, 0.f};

    short8 aP0[2], aP1[2], bbE[4][2], bbO[4][2];
    short* b0 = lds;
    short* b1 = lds + BUFSH;
    short* b2 = lds + 2 * BUFSH;
    const int nt = Ks >> 6;

    #pragma unroll
    for (int i = 0; i < 6; ++i) STAGEU(i, 0, b0);
    #pragma unroll
    for (int i = 0; i < 6; ++i) STAGEU(i, 1, b1);
    WAITV6; BARR; SB;
    RD_B(bbE, b0); RD_A(aP0, b0, 0);

    short *CURB = b0, *NXTB = b1, *THDB = b2;
    for (int t = 0; t < nt; t += 2) {
        TILE(t, CURB, NXTB, THDB, bbE, bbO);
        { short* tmp = CURB; CURB = NXTB; NXTB = THDB; THDB = tmp; }
        TILE(t + 1, CURB, NXTB, THDB, bbO, bbE);
        { short* tmp = CURB; CURB = NXTB; NXTB = THDB; THDB = tmp; }
    }

    const int r0 = q4 * 4;
    #pragma unroll
    for (int f = 0; f < 4; ++f)
        #pragma unroll
        for (int j = 0; j < 4; ++j)
            #pragma unroll
            for (int r = 0; r < 4; ++r) {
                const int row = m0 + mr + f*16 + r0 + r;
                const int col = n0 + nc + j*16 + cc;
                if (OUT_BF16)
                    ((u16*)Cw)[(size_t)row * ldc + col] = f2bf(acc[f][j][r]);
                else
                    ((float*)Cw)[(size_t)row * ldc + col] = acc[f][j][r];
            }
}

// ---------------------------------------------------------------------------
// Fused prep: RMSNorm+RoPE q/K (q in place, K packed swizzled) + V
// transpose-pack (64-s layout). 256 blocks: tile = bid&31, kvh = bid>>5.
// ---------------------------------------------------------------------------
__global__ __launch_bounds__(256) void prep(
    u16* __restrict__ qkv, const int* __restrict__ positions,
    const float* __restrict__ qw, const float* __restrict__ kw,
    u16* __restrict__ Kp, u16* __restrict__ Vtp)
{
    const int bid = blockIdx.x;
    const int tile = bid & 31, kvh = bid >> 5;
    const int tid = threadIdx.x;
    const int w = tid >> 6, l = tid & 63;
    const int t0 = tile * 64;

    const float qw0 = qw[2*l], qw1 = qw[2*l+1];
    const float kw0 = kw[2*l], kw1 = kw[2*l+1];
    const int   i0  = (2*l) & 63;
    const float if0 = exp2f(-(float)i0     * 0.311430758895690f); // log2(1e6)/64
    const float if1 = exp2f(-(float)(i0+1) * 0.311430758895690f);

    for (int rr = w; rr < 64; rr += 4) {
        const int t = t0 + rr;
        const int pos = positions[t];
        const float a0 = (float)pos * if0;
        const float a1 = (float)pos * if1;
        const float s0 = sinf(a0), c0 = cosf(a0);
        const float s1 = sinf(a1), c1 = cosf(a1);

        #pragma unroll
        for (int pass = 0; pass < 3; ++pass) {
            const int off = (pass < 2) ? (2*kvh + pass)*HD : NH*HD + kvh*HD;
            const float w0 = (pass < 2) ? qw0 : kw0;
            const float w1 = (pass < 2) ? qw1 : kw1;
            u16* p = qkv + (size_t)t*QKV_N + off;

            const u32 pk = *(const u32*)(p + 2*l);
            const float x0 = bf2f((u16)pk), x1 = bf2f((u16)(pk >> 16));
            float ss = x0*x0 + x1*x1;
            #pragma unroll
            for (int x = 1; x < 64; x <<= 1) ss += __shfl_xor(ss, x);
            const float rs = rsqrtf(ss * (1.0f/128.0f) + EPS);
            const float xn0 = x0 * rs * w0, xn1 = x1 * rs * w1;
            const float px0 = __shfl_xor(xn0, 32);
            const float px1 = __shfl_xor(xn1, 32);

            float o0, o1;
            if (l < 32) { o0 = xn0*c0 - px0*s0; o1 = xn1*c1 - px1*s1; }
            else        { o0 = xn0*c0 + px0*s0; o1 = xn1*c1 + px1*s1; }
            const u32 outpk = (u32)f2bf(o0) | ((u32)f2bf(o1) << 16);

            if (pass < 2) {
                *(u32*)(p + 2*l) = outpk;
            } else {
                const int ch = l >> 2;
                u16* dst = Kp + ((size_t)(kvh*32 + tile)*64 + rr)*128
                              + (ch ^ (rr & 15))*8 + (l & 3)*2;
                *(u32*)dst = outpk;
            }
        }
    }

    // ---- V transpose + swizzled pack (64-s layout) ----
    __shared__ u16 tl[64][136];
    {
        const int t  = tid >> 2;
        const int c0 = (tid & 3) * 32;
        const u16* src = qkv + (size_t)(t0 + t)*QKV_N + NH*HD + NKV*HD + kvh*HD + c0;
        #pragma unroll
        for (int p2 = 0; p2 < 4; ++p2)
            *(u16x8*)(&tl[t][c0 + p2*8]) = *(const u16x8*)(src + p2*8);
    }
    __syncthreads();
    {
        u16* dstb = Vtp + (size_t)(kvh*32 + tile) * 128 * 64;
        #pragma unroll
        for (int i = 0; i < 4; ++i) {
            const int id = tid*4 + i;
            const int d = id >> 3;
            const int o = id & 7;
            const int sb = (o ^ (d & 7)) * 8;
            u16x8 v;
            #pragma unroll
            for (int j = 0; j < 8; ++j) v[j] = tl[sb + j][d];
            *(u16x8*)(dstb + d*64 + o*8) = v;
        }
    }
}

// ---------------------------------------------------------------------------
// 32x32-MFMA flash attention, 8-WAVE BLOCKS: 512 thr, q-tile=256 (32 q/wave,
// per-wave body identical to the proven round-2 kernel, VGPR 112),
// kv-tile=64 double-buffered, one head/block. 8 waves share each staged
// K/V tile -> tile-visits halve chip-wide at constant per-CU LDS-read bytes.
// __launch_bounds__(512,2): empirical hipcc rule cap = 256/minwaves -> 128,
// >= the 112 needed (round-8's (512,4) imposed cap 64 -> cascade spill).
// Occupancy unchanged: LDS (64 KB) already limits to 2 blocks/CU.
// Split-s 4 parts (nt = 4qt+4 divides evenly). grid 512 = 8 kvh x 2 hp x
// 4 part x 4 q3 x 2 top; top pairs qt = q3 with 7-q3 (9 tiles per pair).
// ---------------------------------------------------------------------------
__global__ __launch_bounds__(512, 2) void attn_mfma32(
    const u16* __restrict__ qkv, const u16* __restrict__ Kp,
    const u16* __restrict__ Vtp,
    u16* __restrict__ P0, u16* __restrict__ P1,
    u16* __restrict__ P2, u16* __restrict__ P3,
    float2* __restrict__ ml)
{
    const int id  = blockIdx.x;          // 0..511
    const int kvh = id & 7;
    const int u   = id >> 3;             // 0..63
    const int hp  = u & 1;
    const int p   = (u >> 1) & 3;        // split-s part
    const int q3  = (u >> 3) & 3;
    const int top = u >> 5;
    const int qt  = top ? 7 - q3 : q3;   // 0..7, q-tile of 256 rows
    const int h   = kvh*2 + hp;
    const int t0q = qt * 256;

    const int tid = threadIdx.x;
    const int w   = tid >> 6;       // wave 0..7 owns q rows [w*32, w*32+32)
    const int l   = tid & 63;
    const int q31 = l & 31;
    const int hi  = l >> 5;

    __shared__ short Ks[2][8192];   // 2 x 16 KB (64 kv x 128 d, chunk-swz)
    __shared__ short Vts[2][8192];  // 2 x 16 KB (128 d x 64 s, chunk-swz)

    // ---- Q B-frags in registers ----
    short8 qf[8];
    {
        const u16* qrow = qkv + (size_t)(t0q + w*32 + q31) * QKV_N + h*HD;
        #pragma unroll
        for (int ks = 0; ks < 8; ++ks)
            qf[ks] = *(const short8*)(qrow + ks*16 + hi*8);
    }

    float m_run = -3.0e38f, l_run = 0.f;
    f32x16 accO[4];                 // O[q rows via reg][d = nd*32 + q31]
    #pragma unroll
    for (int nd = 0; nd < 4; ++nd)
        #pragma unroll
        for (int r = 0; r < 16; ++r) accO[nd][r] = 0.f;

    const float Cs = 0.12751744f;   // (1/sqrt(128)) * log2(e)

    const int nt  = 4*qt + 4;
    const int tlo = p * (qt + 1);   // nt/4 == qt+1 exactly
    const int thi = tlo + (qt + 1);

    // 8 waves stage 32 KB: waves 0-3 K image, waves 4-7 Vt image (4 KB each).
    auto issue = [&](int tile, int buf) {
        const size_t tb = (size_t)(kvh*32 + tile) * 8192;
        const u16* g = ((w < 4) ? Kp : Vtp) + tb + (w & 3)*2048 + l*8;
        short* pl = ((w < 4) ? Ks[buf] : Vts[buf]) + (w & 3)*2048 + l*8;
        #pragma unroll
        for (int i = 0; i < 4; ++i)
            __builtin_amdgcn_global_load_lds(
                (const __attribute__((address_space(1))) u32*)(g + i*512),
                (__attribute__((address_space(3))) u32*)(pl + i*512), 16, 0, 0);
    };

    issue(tlo, 0);
    int cur = 0;

    for (int tile = tlo; tile < thi; ++tile) {
        __syncthreads();            // drains buf[cur] DMA
        if (tile + 1 < thi) issue(tile + 1, cur ^ 1);

        const short* Kc = Ks[cur];
        const short* Vc = Vts[cur];

        // ---- S^T = K Q^T ----
        f32x16 accS0, accS1;
        #pragma unroll
        for (int r = 0; r < 16; ++r) { accS0[r] = 0.f; accS1[r] = 0.f; }

        __builtin_amdgcn_s_setprio(1);
        #pragma unroll
        for (int ks = 0; ks < 8; ++ks) {
            const int pc = ((2*ks + hi) ^ (q31 & 15)) * 8;
            short8 a0 = *(const short8*)(Kc + q31*128 + pc);
            short8 a1 = *(const short8*)(Kc + (32 + q31)*128 + pc);
            accS0 = __builtin_amdgcn_mfma_f32_32x32x16_bf16(a0, qf[ks], accS0, 0, 0, 0);
            accS1 = __builtin_amdgcn_mfma_f32_32x32x16_bf16(a1, qf[ks], accS1, 0, 0, 0);
        }
        __builtin_amdgcn_s_setprio(0);

        // ---- causal mask (diagonal region: tile >= 4*qt) ----
        if (tile >= 4*qt) {
            const int qg   = t0q + w*32 + q31;
            const int kvb0 = tile*64 + (hi << 2);
            #pragma unroll
            for (int r = 0; r < 16; ++r) {
                const int kvg = kvb0 + (r&3) + 8*(r>>2);
                if (kvg > qg)      accS0[r] = -1.0e30f;
                if (kvg + 32 > qg) accS1[r] = -1.0e30f;
            }
        }

        // ---- online softmax (per q col = lane pair l, l^32) ----
        float mx = accS0[0];
        #pragma unroll
        for (int r = 1; r < 16; ++r) mx = fmaxf(mx, accS0[r]);
        #pragma unroll
        for (int r = 0; r < 16; ++r) mx = fmaxf(mx, accS1[r]);
        mx = fmaxf(mx, __shfl_xor(mx, 32));

        if (__any(mx > m_run + 11.76f)) {   // T13 defer-max
            const float m_new = fmaxf(m_run, mx);
            const float alpha = exp2f((m_run - m_new) * Cs);
            l_run *= alpha;
            m_run = m_new;
            #pragma unroll
            for (int r = 0; r < 16; ++r) {
                const float ar = __shfl(alpha, ((r&3) + 8*(r>>2)) + (hi<<2));
                accO[0][r] *= ar; accO[1][r] *= ar;
                accO[2][r] *= ar; accO[3][r] *= ar;
            }
        }

        const float mb = m_run * Cs;
        float lsum = 0.f;
        #pragma unroll
        for (int r = 0; r < 16; ++r) {
            const float e0 = exp2f(accS0[r]*Cs - mb);
            const float e1 = exp2f(accS1[r]*Cs - mb);
            accS0[r] = e0; accS1[r] = e1;
            lsum += e0 + e1;
        }
        lsum += __shfl_xor(lsum, 32);
        l_run += lsum;

        // ---- PV: O[q][d] += P[q][s] Vt[d][s]; A-frag via cvt_pk+permlane ----
        __builtin_amdgcn_s_setprio(1);
        #pragma unroll
        for (int ks = 0; ks < 4; ++ks) {
            const int R = (ks & 1) * 8;
            u32 x0, x1, x2, x3;
            if (ks < 2) {
                x0 = cvtpk_bf16(accS0[R+0], accS0[R+1]);
                x1 = cvtpk_bf16(accS0[R+2], accS0[R+3]);
                x2 = cvtpk_bf16(accS0[R+4], accS0[R+5]);
                x3 = cvtpk_bf16(accS0[R+6], accS0[R+7]);
            } else {
                x0 = cvtpk_bf16(accS1[R+0], accS1[R+1]);
                x1 = cvtpk_bf16(accS1[R+2], accS1[R+3]);
                x2 = cvtpk_bf16(accS1[R+4], accS1[R+5]);
                x3 = cvtpk_bf16(accS1[R+6], accS1[R+7]);
            }
            asm("v_permlane32_swap_b32 %0, %1" : "+v"(x0), "+v"(x2));
            asm("v_permlane32_swap_b32 %0, %1" : "+v"(x1), "+v"(x3));
            u32x4 aw; aw.x = x0; aw.y = x1; aw.z = x2; aw.w = x3;
            const short8 aP = __builtin_bit_cast(short8, aw);
            #pragma unroll
            for (int nd = 0; nd < 4; ++nd) {
                short8 bv = *(const short8*)(Vc + (nd*32 + q31)*64
                                             + ((2*ks + hi) ^ (q31 & 7))*8);
                accO[nd] = __builtin_amdgcn_mfma_f32_32x32x16_bf16(aP, bv, accO[nd], 0, 0, 0);
            }
        }
        __builtin_amdgcn_s_setprio(0);

        cur ^= 1;
    }

    // ---- write UNNORMALIZED partial + (m,l) per q row ----
    u16* Op = (p == 0) ? P0 : (p == 1) ? P1 : (p == 2) ? P2 : P3;
    const size_t hb = (size_t)h * T_TOK;
    #pragma unroll
    for (int r = 0; r < 16; ++r) {
        const int qr = (r&3) + 8*(r>>2) + (hi<<2);
        u16* op = Op + (hb + t0q + w*32 + qr) * HD;
        op[q31]      = f2bf(accO[0][r]);
        op[32 + q31] = f2bf(accO[1][r]);
        op[64 + q31] = f2bf(accO[2][r]);
        op[96 + q31] = f2bf(accO[3][r]);
    }
    if (l < 32)
        ml[(size_t)p*NH*T_TOK + hb + t0q + w*32 + l]
            = make_float2(m_run, l_run);
}

// ---------------------------------------------------------------------------
// Merge the four split-s partials -> q slot of qkv (bf16), 8 elems/thread,
// blocks [0,2048). Blocks [2048,4096): o_w f32->bf16 cvt into kpb.
// ---------------------------------------------------------------------------
__global__ __launch_bounds__(256) void combine4_cvt(
    const u16* __restrict__ P0, const u16* __restrict__ P1,
    const u16* __restrict__ P2, const u16* __restrict__ P3,
    const float2* __restrict__ ml, u16* __restrict__ qkv,
    const float* __restrict__ ow, u16* __restrict__ owbf)
{
    const int bid = blockIdx.x;
    if (bid >= 2048) {
        cvt8(ow, owbf, ((size_t)(bid - 2048) * 256 + threadIdx.x) * 8);
        return;
    }
    const int idx = bid * 256 + threadIdx.x;
    const int c16 = idx & 15;
    const int t   = (idx >> 4) & (T_TOK - 1);
    const int h   = idx >> 15;
    const size_t base = (size_t)h * T_TOK + t;
    const size_t NT = (size_t)NH * T_TOK;
    const float2 a = ml[base];
    const float2 b = ml[base + NT];
    const float2 c = ml[base + 2*NT];
    const float2 d = ml[base + 3*NT];
    const float Cs = 0.12751744f;
    const float mM = fmaxf(fmaxf(a.x, b.x), fmaxf(c.x, d.x));
    const float wA = exp2f((a.x - mM) * Cs);
    const float wB = exp2f((b.x - mM) * Cs);
    const float wC = exp2f((c.x - mM) * Cs);
    const float wD = exp2f((d.x - mM) * Cs);
    const float inv = 1.0f / (wA*a.y + wB*b.y + wC*c.y + wD*d.y);
    const u16x8 A = *(const u16x8*)(P0 + base * HD + c16*8);
    const u16x8 B = *(const u16x8*)(P1 + base * HD + c16*8);
    const u16x8 C = *(const u16x8*)(P2 + base * HD + c16*8);
    const u16x8 D = *(const u16x8*)(P3 + base * HD + c16*8);
    u16x8 o;
    #pragma unroll
    for (int j = 0; j < 8; ++j)
        o[j] = f2bf((wA*bf2f(A[j]) + wB*bf2f(B[j]) + wC*bf2f(C[j]) + wD*bf2f(D[j])) * inv);
    *(u16x8*)(qkv + (size_t)t * QKV_N + h * HD + c16*8) = o;
}

// ---------------------------------------------------------------------------
extern "C" void kernel_launch(void* const* d_in, const int* in_sizes, int n_in,
                              void* d_out, int out_size, void* d_ws, size_t ws_size,
                              hipStream_t stream)
{
    const float* hidden    = (const float*)d_in[0];   // T x HID
    const int*   positions = (const int*)  d_in[1];   // T
    const float* qkv_w     = (const float*)d_in[2];   // 4096 x 2048
    const float* o_w       = (const float*)d_in[3];   // 2048 x 2048
    const float* q_norm_w  = (const float*)d_in[4];   // 128
    const float* k_norm_w  = (const float*)d_in[5];   // 128
    float* out = (float*)d_out;                       // T x HID (f32)

    // ws: [qkvbf 16MB][wbf 16MB][abf 8MB][kpb 4MB][vpb 4MB] = 48 MB
    // During attn: P0/P1 -> wbf halves, P2 -> abf, P3 -> out[0:8MB],
    // ml -> out[8:12MB]. o_w bf16 -> kpb+vpb (8 MB) during combine launch.
    // gemm2: B = kpb, split-K partial -> wbf (dead after combine).
    u16* qkvbf = (u16*)d_ws;
    u16* wbf   = qkvbf + (size_t)T_TOK * QKV_N;
    u16* abf   = wbf   + (size_t)QKV_N * HID;
    u16* kpb   = abf   + (size_t)T_TOK * HID;
    u16* vpb   = kpb   + (size_t)NKV * T_TOK * HD;

    u16* P0 = wbf;
    u16* P1 = wbf + (size_t)NH * T_TOK * HD;   // wbf second half
    u16* P2 = abf;
    u16* P3 = (u16*)out;
    float2* mlp = (float2*)((u16*)out + (size_t)NH * T_TOK * HD);
    float* partC = (float*)wbf;     // 2048x2048 f32 = 16 MB (fits wbf exactly)

    static bool s_attr = false;
    if (!s_attr) {
        (void)hipFuncSetAttribute(
            reinterpret_cast<const void*>(&gemm_bt_8p<true>),
            hipFuncAttributeMaxDynamicSharedMemorySize, 147456);
        (void)hipFuncSetAttribute(
            reinterpret_cast<const void*>(&gemm_bt_8p<false>),
            hipFuncAttributeMaxDynamicSharedMemorySize, 147456);
        s_attr = true;
    }

    // 0) hidden + qkv_w -> bf16 (one launch)
    cvt_pair<<<6144, 256, 0, stream>>>(hidden, abf, qkv_w, wbf);

    // 1) qkv(bf16) = hidden @ qkv_w^T   (no k-split)
    gemm_bt_8p<true><<<dim3(QKV_N/GBN, T_TOK/GBM, 1), 512, 147456, stream>>>(
        abf, wbf, qkvbf, qkvbf, HID, HID, HID, QKV_N);

    // 2) prep (rmsnorm+rope, K/V pack; V 64-s layout)
    prep<<<256, 256, 0, stream>>>(qkvbf, positions, q_norm_w, k_norm_w, kpb, vpb);

    // 3) 8-wave q-tile-256 split-4 flash attention (2 blocks/CU, no spill)
    attn_mfma32<<<512, 512, 0, stream>>>(qkvbf, kpb, vpb, P0, P1, P2, P3, mlp);

    // 3b) combine partials -> q slots of qkv; o_w -> bf16 into kpb(+vpb)
    combine4_cvt<<<4096, 256, 0, stream>>>(P0, P1, P2, P3, mlp, qkvbf, o_w, kpb);

    // 4) out(f32) = o @ o_w^T, split-K=2 over z: z=0 -> out, z=1 -> partC
    gemm_bt_8p<false><<<dim3(HID/GBN, T_TOK/GBM, 2), 512, 147456, stream>>>(
        qkvbf, kpb, out, partC, HID/2, QKV_N, HID, HID);

    // 4b) out += partC
    addf32<<<(T_TOK*HID)/2048, 256, 0, stream>>>(out, partC);
}

// Round 10
// 242.245 us; speedup vs baseline: 1.1651x; 1.0159x over previous
//
#include <hip/hip_runtime.h>
#include <math.h>

// Qwen3Attention: T=2048, HID=2048, H=16, KV=8, D=128
#define T_TOK 2048
#define HID 2048
#define NH 16
#define NKV 8
#define HD 128
#define QKV_N 4096
#define EPS 1e-6f

typedef unsigned short u16;
typedef unsigned int   u32;
typedef __attribute__((ext_vector_type(8))) u16   u16x8;
typedef __attribute__((ext_vector_type(8))) short short8;
typedef __attribute__((ext_vector_type(4))) float floatx4;
typedef __attribute__((ext_vector_type(16))) float f32x16;
typedef __attribute__((ext_vector_type(4))) u32   u32x4;

__device__ __forceinline__ u16 f2bf(float x) {           // RNE f32->bf16
    u32 u = __float_as_uint(x);
    u = (u + 0x7fffu + ((u >> 16) & 1u)) >> 16;
    return (u16)u;
}
__device__ __forceinline__ float bf2f(u16 h) {
    return __uint_as_float(((u32)h) << 16);
}
__device__ __forceinline__ u32 cvtpk_bf16(float lo, float hi) {
    u32 r;
    asm("v_cvt_pk_bf16_f32 %0, %1, %2" : "=v"(r) : "v"(lo), "v"(hi));
    return r;
}

// ---------------------------------------------------------------------------
// f32 -> bf16, 8 elems/thread helper.
// ---------------------------------------------------------------------------
__device__ __forceinline__ void cvt8(const float* __restrict__ in,
                                     u16* __restrict__ out, size_t i)
{
    float4 a = *(const float4*)(in + i);
    float4 b = *(const float4*)(in + i + 4);
    u16x8 o;
    o[0] = f2bf(a.x); o[1] = f2bf(a.y); o[2] = f2bf(a.z); o[3] = f2bf(a.w);
    o[4] = f2bf(b.x); o[5] = f2bf(b.y); o[6] = f2bf(b.z); o[7] = f2bf(b.w);
    *(u16x8*)(out + i) = o;
}

// hidden (2048 blk) + qkv_w (4096 blk) in one launch.
__global__ __launch_bounds__(256) void cvt_pair(
    const float* __restrict__ ina, u16* __restrict__ outa,
    const float* __restrict__ inb, u16* __restrict__ outb)
{
    const int bid = blockIdx.x;
    if (bid < 2048) cvt8(ina, outa, ((size_t)bid * 256 + threadIdx.x) * 8);
    else            cvt8(inb, outb, ((size_t)(bid - 2048) * 256 + threadIdx.x) * 8);
}

// ---------------------------------------------------------------------------
// bf16 MFMA GEMM, T2+T3+T4+T5 stack: C[M,N] = A[M,K]*B[N,K]^T
// (split-K machinery retained in signature; launched non-split: z=1.
//  r5-vs-r2 A/B showed split-K + addf32 is net-negative ~4.5 us.)
// ---------------------------------------------------------------------------
#define GBM 256
#define GBN 128
#define GBK 64
#define BUFSH 24576

#define WAITV6 asm volatile("s_waitcnt vmcnt(6)" ::: "memory")
#define WAITV0 asm volatile("s_waitcnt vmcnt(0)" ::: "memory")
#define LGKM0  asm volatile("s_waitcnt lgkmcnt(0)" ::: "memory")
#define BARR   asm volatile("s_barrier" ::: "memory")
#define SB     __builtin_amdgcn_sched_barrier(0)

#define STAGEU(i, tt, dstb) \
    __builtin_amdgcn_global_load_lds( \
        (const __attribute__((address_space(1))) u32*)(gsrc[i] + (size_t)(tt)*GBK), \
        (__attribute__((address_space(3))) u32*)((dstb) + loff[i]), 16, 0, 0)

#define RD_A(dst, srcb, f) do { \
    dst[0] = *(const short8*)((srcb) + arow + (f)*1024 + achunk0); \
    dst[1] = *(const short8*)((srcb) + arow + (f)*1024 + achunk1); } while (0)

#define RD_B(dst, srcb) do { \
    _Pragma("unroll") \
    for (int j_ = 0; j_ < 4; ++j_) { \
        dst[j_][0] = *(const short8*)((srcb) + 16384 + brow + j_*1024 + achunk0); \
        dst[j_][1] = *(const short8*)((srcb) + 16384 + brow + j_*1024 + achunk1); } } while (0)

#define MM(f, aa, bb) do { \
    __builtin_amdgcn_s_setprio(1); \
    _Pragma("unroll") \
    for (int j_ = 0; j_ < 4; ++j_) { \
        acc[f][j_] = __builtin_amdgcn_mfma_f32_16x16x32_bf16(aa[0], bb[j_][0], acc[f][j_], 0, 0, 0); \
        acc[f][j_] = __builtin_amdgcn_mfma_f32_16x16x32_bf16(aa[1], bb[j_][1], acc[f][j_], 0, 0, 0); } \
    __builtin_amdgcn_s_setprio(0); } while (0)

#define TILE(t, CURB, NXTB, THDB, BBC, BBN) do { \
    const bool st_ = (t) + 2 < nt; \
    if (st_) { STAGEU(0, (t)+2, THDB); STAGEU(1, (t)+2, THDB); } \
    RD_A(aP1, CURB, 1); SB; \
    MM(0, aP0, BBC); SB; \
    if (st_) { STAGEU(2, (t)+2, THDB); STAGEU(3, (t)+2, THDB); } \
    RD_A(aP0, CURB, 2); SB; \
    MM(1, aP1, BBC); SB; \
    if (st_) { STAGEU(4, (t)+2, THDB); STAGEU(5, (t)+2, THDB); } \
    RD_A(aP1, CURB, 3); SB; \
    MM(2, aP0, BBC); \
    if ((t) + 1 < nt) { \
        if (st_) { WAITV6; } else { WAITV0; } \
        LGKM0; BARR; SB; \
        RD_B(BBN, NXTB); RD_A(aP0, NXTB, 0); \
    } \
    SB; \
    MM(3, aP1, BBC); SB; \
} while (0)

template<bool OUT_BF16>
__global__ __launch_bounds__(512, 2) void gemm_bt_8p(
    const u16* __restrict__ A, const u16* __restrict__ B,
    void* __restrict__ Cv, void* __restrict__ Cv2,
    int Ks, int lda, int ldb, int ldc)
{
    extern __shared__ short lds[];
    const int tid = threadIdx.x;
    const int w  = tid >> 6;
    const int l  = tid & 63;
    const int m0 = blockIdx.y * GBM;
    const int n0 = blockIdx.x * GBN;
    const int z  = blockIdx.z;
    A += (size_t)z * Ks;                    // k-offset within rows
    B += (size_t)z * Ks;
    void* Cw = z ? Cv2 : Cv;
    const int mr = (w >> 1) * 64;
    const int nc = (w & 1) * 64;
    const int cc = l & 15;
    const int q4 = l >> 4;

    const int lr = l >> 3;
    const int gchunk = ((l & 7) ^ (lr & 7)) * 8;
    const u16* gsrc[6]; int loff[6];
    #pragma unroll
    for (int i = 0; i < 6; ++i) {
        const int u = w * 6 + i;
        if (u < 32) {
            gsrc[i] = A + (size_t)(m0 + u*8 + lr) * lda + gchunk;
            loff[i] = u * 512;
        } else {
            const int v = u - 32;
            gsrc[i] = B + (size_t)(n0 + v*8 + lr) * ldb + gchunk;
            loff[i] = 16384 + v * 512;
        }
    }

    const int achunk0 = ((q4)     ^ (cc & 7)) * 8;
    const int achunk1 = ((4 + q4) ^ (cc & 7)) * 8;
    const int arow = (mr + cc) * 64;
    const int brow = (nc + cc) * 64;

    floatx4 acc[4][4];
    #pragma unroll
    for (int f = 0; f < 4; ++f)
        #pragma unroll
        for (int j = 0; j < 4; ++j) acc[f][j] = (floatx4){0.f, 0.f, 0.f, 0.f};

    short8 aP0[2], aP1[2], bbE[4][2], bbO[4][2];
    short* b0 = lds;
    short* b1 = lds + BUFSH;
    short* b2 = lds + 2 * BUFSH;
    const int nt = Ks >> 6;

    #pragma unroll
    for (int i = 0; i < 6; ++i) STAGEU(i, 0, b0);
    #pragma unroll
    for (int i = 0; i < 6; ++i) STAGEU(i, 1, b1);
    WAITV6; BARR; SB;
    RD_B(bbE, b0); RD_A(aP0, b0, 0);

    short *CURB = b0, *NXTB = b1, *THDB = b2;
    for (int t = 0; t < nt; t += 2) {
        TILE(t, CURB, NXTB, THDB, bbE, bbO);
        { short* tmp = CURB; CURB = NXTB; NXTB = THDB; THDB = tmp; }
        TILE(t + 1, CURB, NXTB, THDB, bbO, bbE);
        { short* tmp = CURB; CURB = NXTB; NXTB = THDB; THDB = tmp; }
    }

    const int r0 = q4 * 4;
    #pragma unroll
    for (int f = 0; f < 4; ++f)
        #pragma unroll
        for (int j = 0; j < 4; ++j)
            #pragma unroll
            for (int r = 0; r < 4; ++r) {
                const int row = m0 + mr + f*16 + r0 + r;
                const int col = n0 + nc + j*16 + cc;
                if (OUT_BF16)
                    ((u16*)Cw)[(size_t)row * ldc + col] = f2bf(acc[f][j][r]);
                else
                    ((float*)Cw)[(size_t)row * ldc + col] = acc[f][j][r];
            }
}

// ---------------------------------------------------------------------------
// Fused prep: RMSNorm+RoPE q/K (q in place, K packed swizzled) + V
// transpose-pack (64-s layout). 256 blocks: tile = bid&31, kvh = bid>>5.
// ---------------------------------------------------------------------------
__global__ __launch_bounds__(256) void prep(
    u16* __restrict__ qkv, const int* __restrict__ positions,
    const float* __restrict__ qw, const float* __restrict__ kw,
    u16* __restrict__ Kp, u16* __restrict__ Vtp)
{
    const int bid = blockIdx.x;
    const int tile = bid & 31, kvh = bid >> 5;
    const int tid = threadIdx.x;
    const int w = tid >> 6, l = tid & 63;
    const int t0 = tile * 64;

    const float qw0 = qw[2*l], qw1 = qw[2*l+1];
    const float kw0 = kw[2*l], kw1 = kw[2*l+1];
    const int   i0  = (2*l) & 63;
    const float if0 = exp2f(-(float)i0     * 0.311430758895690f); // log2(1e6)/64
    const float if1 = exp2f(-(float)(i0+1) * 0.311430758895690f);

    for (int rr = w; rr < 64; rr += 4) {
        const int t = t0 + rr;
        const int pos = positions[t];
        const float a0 = (float)pos * if0;
        const float a1 = (float)pos * if1;
        const float s0 = sinf(a0), c0 = cosf(a0);
        const float s1 = sinf(a1), c1 = cosf(a1);

        #pragma unroll
        for (int pass = 0; pass < 3; ++pass) {
            const int off = (pass < 2) ? (2*kvh + pass)*HD : NH*HD + kvh*HD;
            const float w0 = (pass < 2) ? qw0 : kw0;
            const float w1 = (pass < 2) ? qw1 : kw1;
            u16* p = qkv + (size_t)t*QKV_N + off;

            const u32 pk = *(const u32*)(p + 2*l);
            const float x0 = bf2f((u16)pk), x1 = bf2f((u16)(pk >> 16));
            float ss = x0*x0 + x1*x1;
            #pragma unroll
            for (int x = 1; x < 64; x <<= 1) ss += __shfl_xor(ss, x);
            const float rs = rsqrtf(ss * (1.0f/128.0f) + EPS);
            const float xn0 = x0 * rs * w0, xn1 = x1 * rs * w1;
            const float px0 = __shfl_xor(xn0, 32);
            const float px1 = __shfl_xor(xn1, 32);

            float o0, o1;
            if (l < 32) { o0 = xn0*c0 - px0*s0; o1 = xn1*c1 - px1*s1; }
            else        { o0 = xn0*c0 + px0*s0; o1 = xn1*c1 + px1*s1; }
            const u32 outpk = (u32)f2bf(o0) | ((u32)f2bf(o1) << 16);

            if (pass < 2) {
                *(u32*)(p + 2*l) = outpk;
            } else {
                const int ch = l >> 2;
                u16* dst = Kp + ((size_t)(kvh*32 + tile)*64 + rr)*128
                              + (ch ^ (rr & 15))*8 + (l & 3)*2;
                *(u32*)dst = outpk;
            }
        }
    }

    // ---- V transpose + swizzled pack (64-s layout) ----
    __shared__ u16 tl[64][136];
    {
        const int t  = tid >> 2;
        const int c0 = (tid & 3) * 32;
        const u16* src = qkv + (size_t)(t0 + t)*QKV_N + NH*HD + NKV*HD + kvh*HD + c0;
        #pragma unroll
        for (int p2 = 0; p2 < 4; ++p2)
            *(u16x8*)(&tl[t][c0 + p2*8]) = *(const u16x8*)(src + p2*8);
    }
    __syncthreads();
    {
        u16* dstb = Vtp + (size_t)(kvh*32 + tile) * 128 * 64;
        #pragma unroll
        for (int i = 0; i < 4; ++i) {
            const int id = tid*4 + i;
            const int d = id >> 3;
            const int o = id & 7;
            const int sb = (o ^ (d & 7)) * 8;
            u16x8 v;
            #pragma unroll
            for (int j = 0; j < 8; ++j) v[j] = tl[sb + j][d];
            *(u16x8*)(dstb + d*64 + o*8) = v;
        }
    }
}

// ---------------------------------------------------------------------------
// 32x32-MFMA flash attention, 8-WAVE BLOCKS: 512 thr, q-tile=256 (32 q/wave,
// per-wave body identical to the proven round-2 kernel, VGPR 112),
// kv-tile=64 double-buffered, one head/block. 8 waves share each staged
// K/V tile -> tile-visits halve chip-wide at constant per-CU LDS-read bytes.
// __launch_bounds__(512,2): empirical hipcc rule cap = 256/minwaves -> 128,
// >= the 112 needed. LDS (64 KB) limits to 2 blocks/CU.
// Split-s 4 parts (nt = 4qt+4 divides evenly). grid 512 = 8 kvh x 2 hp x
// 4 part x 4 q3 x 2 top; top pairs qt = q3 with 7-q3 (9 tiles per pair).
// ---------------------------------------------------------------------------
__global__ __launch_bounds__(512, 2) void attn_mfma32(
    const u16* __restrict__ qkv, const u16* __restrict__ Kp,
    const u16* __restrict__ Vtp,
    u16* __restrict__ P0, u16* __restrict__ P1,
    u16* __restrict__ P2, u16* __restrict__ P3,
    float2* __restrict__ ml)
{
    const int id  = blockIdx.x;          // 0..511
    const int kvh = id & 7;
    const int u   = id >> 3;             // 0..63
    const int hp  = u & 1;
    const int p   = (u >> 1) & 3;        // split-s part
    const int q3  = (u >> 3) & 3;
    const int top = u >> 5;
    const int qt  = top ? 7 - q3 : q3;   // 0..7, q-tile of 256 rows
    const int h   = kvh*2 + hp;
    const int t0q = qt * 256;

    const int tid = threadIdx.x;
    const int w   = tid >> 6;       // wave 0..7 owns q rows [w*32, w*32+32)
    const int l   = tid & 63;
    const int q31 = l & 31;
    const int hi  = l >> 5;

    __shared__ short Ks[2][8192];   // 2 x 16 KB (64 kv x 128 d, chunk-swz)
    __shared__ short Vts[2][8192];  // 2 x 16 KB (128 d x 64 s, chunk-swz)

    // ---- Q B-frags in registers ----
    short8 qf[8];
    {
        const u16* qrow = qkv + (size_t)(t0q + w*32 + q31) * QKV_N + h*HD;
        #pragma unroll
        for (int ks = 0; ks < 8; ++ks)
            qf[ks] = *(const short8*)(qrow + ks*16 + hi*8);
    }

    float m_run = -3.0e38f, l_run = 0.f;
    f32x16 accO[4];                 // O[q rows via reg][d = nd*32 + q31]
    #pragma unroll
    for (int nd = 0; nd < 4; ++nd)
        #pragma unroll
        for (int r = 0; r < 16; ++r) accO[nd][r] = 0.f;

    const float Cs = 0.12751744f;   // (1/sqrt(128)) * log2(e)

    const int nt  = 4*qt + 4;
    const int tlo = p * (qt + 1);   // nt/4 == qt+1 exactly
    const int thi = tlo + (qt + 1);

    // 8 waves stage 32 KB: waves 0-3 K image, waves 4-7 Vt image (4 KB each).
    auto issue = [&](int tile, int buf) {
        const size_t tb = (size_t)(kvh*32 + tile) * 8192;
        const u16* g = ((w < 4) ? Kp : Vtp) + tb + (w & 3)*2048 + l*8;
        short* pl = ((w < 4) ? Ks[buf] : Vts[buf]) + (w & 3)*2048 + l*8;
        #pragma unroll
        for (int i = 0; i < 4; ++i)
            __builtin_amdgcn_global_load_lds(
                (const __attribute__((address_space(1))) u32*)(g + i*512),
                (__attribute__((address_space(3))) u32*)(pl + i*512), 16, 0, 0);
    };

    issue(tlo, 0);
    int cur = 0;

    for (int tile = tlo; tile < thi; ++tile) {
        __syncthreads();            // drains buf[cur] DMA
        if (tile + 1 < thi) issue(tile + 1, cur ^ 1);

        const short* Kc = Ks[cur];
        const short* Vc = Vts[cur];

        // ---- S^T = K Q^T ----
        f32x16 accS0, accS1;
        #pragma unroll
        for (int r = 0; r < 16; ++r) { accS0[r] = 0.f; accS1[r] = 0.f; }

        __builtin_amdgcn_s_setprio(1);
        #pragma unroll
        for (int ks = 0; ks < 8; ++ks) {
            const int pc = ((2*ks + hi) ^ (q31 & 15)) * 8;
            short8 a0 = *(const short8*)(Kc + q31*128 + pc);
            short8 a1 = *(const short8*)(Kc + (32 + q31)*128 + pc);
            accS0 = __builtin_amdgcn_mfma_f32_32x32x16_bf16(a0, qf[ks], accS0, 0, 0, 0);
            accS1 = __builtin_amdgcn_mfma_f32_32x32x16_bf16(a1, qf[ks], accS1, 0, 0, 0);
        }
        __builtin_amdgcn_s_setprio(0);

        // ---- causal mask (diagonal region: tile >= 4*qt) ----
        if (tile >= 4*qt) {
            const int qg   = t0q + w*32 + q31;
            const int kvb0 = tile*64 + (hi << 2);
            #pragma unroll
            for (int r = 0; r < 16; ++r) {
                const int kvg = kvb0 + (r&3) + 8*(r>>2);
                if (kvg > qg)      accS0[r] = -1.0e30f;
                if (kvg + 32 > qg) accS1[r] = -1.0e30f;
            }
        }

        // ---- online softmax (per q col = lane pair l, l^32) ----
        float mx = accS0[0];
        #pragma unroll
        for (int r = 1; r < 16; ++r) mx = fmaxf(mx, accS0[r]);
        #pragma unroll
        for (int r = 0; r < 16; ++r) mx = fmaxf(mx, accS1[r]);
        mx = fmaxf(mx, __shfl_xor(mx, 32));

        if (__any(mx > m_run + 11.76f)) {   // T13 defer-max
            const float m_new = fmaxf(m_run, mx);
            const float alpha = exp2f((m_run - m_new) * Cs);
            l_run *= alpha;
            m_run = m_new;
            #pragma unroll
            for (int r = 0; r < 16; ++r) {
                const float ar = __shfl(alpha, ((r&3) + 8*(r>>2)) + (hi<<2));
                accO[0][r] *= ar; accO[1][r] *= ar;
                accO[2][r] *= ar; accO[3][r] *= ar;
            }
        }

        const float mb = m_run * Cs;
        float lsum = 0.f;
        #pragma unroll
        for (int r = 0; r < 16; ++r) {
            const float e0 = exp2f(accS0[r]*Cs - mb);
            const float e1 = exp2f(accS1[r]*Cs - mb);
            accS0[r] = e0; accS1[r] = e1;
            lsum += e0 + e1;
        }
        lsum += __shfl_xor(lsum, 32);
        l_run += lsum;

        // ---- PV: O[q][d] += P[q][s] Vt[d][s]; A-frag via cvt_pk+permlane ----
        __builtin_amdgcn_s_setprio(1);
        #pragma unroll
        for (int ks = 0; ks < 4; ++ks) {
            const int R = (ks & 1) * 8;
            u32 x0, x1, x2, x3;
            if (ks < 2) {
                x0 = cvtpk_bf16(accS0[R+0], accS0[R+1]);
                x1 = cvtpk_bf16(accS0[R+2], accS0[R+3]);
                x2 = cvtpk_bf16(accS0[R+4], accS0[R+5]);
                x3 = cvtpk_bf16(accS0[R+6], accS0[R+7]);
            } else {
                x0 = cvtpk_bf16(accS1[R+0], accS1[R+1]);
                x1 = cvtpk_bf16(accS1[R+2], accS1[R+3]);
                x2 = cvtpk_bf16(accS1[R+4], accS1[R+5]);
                x3 = cvtpk_bf16(accS1[R+6], accS1[R+7]);
            }
            asm("v_permlane32_swap_b32 %0, %1" : "+v"(x0), "+v"(x2));
            asm("v_permlane32_swap_b32 %0, %1" : "+v"(x1), "+v"(x3));
            u32x4 aw; aw.x = x0; aw.y = x1; aw.z = x2; aw.w = x3;
            const short8 aP = __builtin_bit_cast(short8, aw);
            #pragma unroll
            for (int nd = 0; nd < 4; ++nd) {
                short8 bv = *(const short8*)(Vc + (nd*32 + q31)*64
                                             + ((2*ks + hi) ^ (q31 & 7))*8);
                accO[nd] = __builtin_amdgcn_mfma_f32_32x32x16_bf16(aP, bv, accO[nd], 0, 0, 0);
            }
        }
        __builtin_amdgcn_s_setprio(0);

        cur ^= 1;
    }

    // ---- write UNNORMALIZED partial + (m,l) per q row ----
    u16* Op = (p == 0) ? P0 : (p == 1) ? P1 : (p == 2) ? P2 : P3;
    const size_t hb = (size_t)h * T_TOK;
    #pragma unroll
    for (int r = 0; r < 16; ++r) {
        const int qr = (r&3) + 8*(r>>2) + (hi<<2);
        u16* op = Op + (hb + t0q + w*32 + qr) * HD;
        op[q31]      = f2bf(accO[0][r]);
        op[32 + q31] = f2bf(accO[1][r]);
        op[64 + q31] = f2bf(accO[2][r]);
        op[96 + q31] = f2bf(accO[3][r]);
    }
    if (l < 32)
        ml[(size_t)p*NH*T_TOK + hb + t0q + w*32 + l]
            = make_float2(m_run, l_run);
}

// ---------------------------------------------------------------------------
// Merge the four split-s partials -> q slot of qkv (bf16), 8 elems/thread,
// blocks [0,2048). Blocks [2048,4096): o_w f32->bf16 cvt into kpb.
// ---------------------------------------------------------------------------
__global__ __launch_bounds__(256) void combine4_cvt(
    const u16* __restrict__ P0, const u16* __restrict__ P1,
    const u16* __restrict__ P2, const u16* __restrict__ P3,
    const float2* __restrict__ ml, u16* __restrict__ qkv,
    const float* __restrict__ ow, u16* __restrict__ owbf)
{
    const int bid = blockIdx.x;
    if (bid >= 2048) {
        cvt8(ow, owbf, ((size_t)(bid - 2048) * 256 + threadIdx.x) * 8);
        return;
    }
    const int idx = bid * 256 + threadIdx.x;
    const int c16 = idx & 15;
    const int t   = (idx >> 4) & (T_TOK - 1);
    const int h   = idx >> 15;
    const size_t base = (size_t)h * T_TOK + t;
    const size_t NT = (size_t)NH * T_TOK;
    const float2 a = ml[base];
    const float2 b = ml[base + NT];
    const float2 c = ml[base + 2*NT];
    const float2 d = ml[base + 3*NT];
    const float Cs = 0.12751744f;
    const float mM = fmaxf(fmaxf(a.x, b.x), fmaxf(c.x, d.x));
    const float wA = exp2f((a.x - mM) * Cs);
    const float wB = exp2f((b.x - mM) * Cs);
    const float wC = exp2f((c.x - mM) * Cs);
    const float wD = exp2f((d.x - mM) * Cs);
    const float inv = 1.0f / (wA*a.y + wB*b.y + wC*c.y + wD*d.y);
    const u16x8 A = *(const u16x8*)(P0 + base * HD + c16*8);
    const u16x8 B = *(const u16x8*)(P1 + base * HD + c16*8);
    const u16x8 C = *(const u16x8*)(P2 + base * HD + c16*8);
    const u16x8 D = *(const u16x8*)(P3 + base * HD + c16*8);
    u16x8 o;
    #pragma unroll
    for (int j = 0; j < 8; ++j)
        o[j] = f2bf((wA*bf2f(A[j]) + wB*bf2f(B[j]) + wC*bf2f(C[j]) + wD*bf2f(D[j])) * inv);
    *(u16x8*)(qkv + (size_t)t * QKV_N + h * HD + c16*8) = o;
}

// ---------------------------------------------------------------------------
extern "C" void kernel_launch(void* const* d_in, const int* in_sizes, int n_in,
                              void* d_out, int out_size, void* d_ws, size_t ws_size,
                              hipStream_t stream)
{
    const float* hidden    = (const float*)d_in[0];   // T x HID
    const int*   positions = (const int*)  d_in[1];   // T
    const float* qkv_w     = (const float*)d_in[2];   // 4096 x 2048
    const float* o_w       = (const float*)d_in[3];   // 2048 x 2048
    const float* q_norm_w  = (const float*)d_in[4];   // 128
    const float* k_norm_w  = (const float*)d_in[5];   // 128
    float* out = (float*)d_out;                       // T x HID (f32)

    // ws: [qkvbf 16MB][wbf 16MB][abf 8MB][kpb 4MB][vpb 4MB] = 48 MB
    // During attn: P0/P1 -> wbf halves, P2 -> abf, P3 -> out[0:8MB],
    // ml -> out[8:12MB]. o_w bf16 -> kpb+vpb (8 MB) during combine launch.
    u16* qkvbf = (u16*)d_ws;
    u16* wbf   = qkvbf + (size_t)T_TOK * QKV_N;
    u16* abf   = wbf   + (size_t)QKV_N * HID;
    u16* kpb   = abf   + (size_t)T_TOK * HID;
    u16* vpb   = kpb   + (size_t)NKV * T_TOK * HD;

    u16* P0 = wbf;
    u16* P1 = wbf + (size_t)NH * T_TOK * HD;   // wbf second half
    u16* P2 = abf;
    u16* P3 = (u16*)out;
    float2* mlp = (float2*)((u16*)out + (size_t)NH * T_TOK * HD);

    static bool s_attr = false;
    if (!s_attr) {
        (void)hipFuncSetAttribute(
            reinterpret_cast<const void*>(&gemm_bt_8p<true>),
            hipFuncAttributeMaxDynamicSharedMemorySize, 147456);
        (void)hipFuncSetAttribute(
            reinterpret_cast<const void*>(&gemm_bt_8p<false>),
            hipFuncAttributeMaxDynamicSharedMemorySize, 147456);
        s_attr = true;
    }

    // 0) hidden + qkv_w -> bf16 (one launch)
    cvt_pair<<<6144, 256, 0, stream>>>(hidden, abf, qkv_w, wbf);

    // 1) qkv(bf16) = hidden @ qkv_w^T   (no k-split)
    gemm_bt_8p<true><<<dim3(QKV_N/GBN, T_TOK/GBM, 1), 512, 147456, stream>>>(
        abf, wbf, qkvbf, qkvbf, HID, HID, HID, QKV_N);

    // 2) prep (rmsnorm+rope, K/V pack; V 64-s layout)
    prep<<<256, 256, 0, stream>>>(qkvbf, positions, q_norm_w, k_norm_w, kpb, vpb);

    // 3) 8-wave q-tile-256 split-4 flash attention (2 blocks/CU, no spill)
    attn_mfma32<<<512, 512, 0, stream>>>(qkvbf, kpb, vpb, P0, P1, P2, P3, mlp);

    // 3b) combine partials -> q slots of qkv; o_w -> bf16 into kpb(+vpb)
    combine4_cvt<<<4096, 256, 0, stream>>>(P0, P1, P2, P3, mlp, qkvbf, o_w, kpb);

    // 4) out(f32) = o @ o_w^T  (non-split: r5-vs-r2 A/B showed split-K
    //    + addf32 is net-negative ~4.5 us)
    gemm_bt_8p<false><<<dim3(HID/GBN, T_TOK/GBM, 1), 512, 147456, stream>>>(
        qkvbf, kpb, out, out, HID, QKV_N, HID, HID);
}